// Round 2
// baseline (211.276 us; speedup 1.0000x reference)
//
#include <hip/hip_runtime.h>
#include <math.h>

#define NB   4096           // histogram bins over (0,1)
#define BLK  256            // threads per block
#define CHW  (NB / BLK)     // 16 bins per chunk
#define CAP  2048           // boundary-bin collection capacity

__global__ void zero_out_kernel(float* __restrict__ out) {
    out[0] = 0.0f;
}

__global__ __launch_bounds__(BLK) void topk_bce_kernel(
    const float* __restrict__ scores,
    const float* __restrict__ label,
    const int*   __restrict__ seqlen,
    float*       __restrict__ out,
    int T, int B)
{
    __shared__ int   cnt[NB];        // 16 KB
    __shared__ float buf[CAP];       // 8 KB
    __shared__ int   schunk[BLK];    // 1 KB
    __shared__ float wsum[BLK / 64];
    __shared__ int   s_b, s_r, s_above, s_ccount;

    const int row = blockIdx.x;
    const int tid = threadIdx.x;
    const int n   = seqlen[row];          // 1..T
    const int k   = (n >> 4) + 1;         // k = n/16 + 1, k <= n always
    const float* rp  = scores + (size_t)row * (size_t)T;
    const float4* rp4 = (const float4*)rp; // row base is 128KB-aligned
    const int n4 = n >> 2;
    const float scale = (float)NB;

#define BIN(x) min(NB - 1, (int)((x) * scale))

    // ---- init ----
    for (int i = tid; i < NB; i += BLK) cnt[i] = 0;
    if (tid == 0) s_ccount = 0;
    __syncthreads();

    // ---- Pass A: count histogram ----
    for (int j = tid; j < n4; j += BLK) {
        float4 v = rp4[j];
        atomicAdd(&cnt[BIN(v.x)], 1);
        atomicAdd(&cnt[BIN(v.y)], 1);
        atomicAdd(&cnt[BIN(v.z)], 1);
        atomicAdd(&cnt[BIN(v.w)], 1);
    }
    for (int j = (n4 << 2) + tid; j < n; j += BLK) {
        atomicAdd(&cnt[BIN(rp[j])], 1);
    }
    __syncthreads();

    // ---- chunk sums (16 bins per thread) ----
    {
        int c = 0;
        const int base = tid * CHW;
        #pragma unroll
        for (int j = 0; j < CHW; ++j) c += cnt[base + j];
        schunk[tid] = c;
    }
    __syncthreads();

    // ---- inclusive suffix scan over 256 chunks (Hillis-Steele) ----
    for (int off = 1; off < BLK; off <<= 1) {
        int v = schunk[tid];
        if (tid + off < BLK) v += schunk[tid + off];
        __syncthreads();
        schunk[tid] = v;
        __syncthreads();
    }

    // ---- locate boundary chunk: SA[t] >= k > SA[t+1] ----
    {
        int SA     = schunk[tid];
        int SAnext = (tid + 1 < BLK) ? schunk[tid + 1] : 0;
        if (SA >= k && SAnext < k) {
            // exactly one thread matches (SA non-increasing, SA[0] = n >= k)
            s_above = SAnext;          // count strictly above this chunk
            s_b     = tid;             // stash chunk id temporarily
        }
    }
    __syncthreads();

    // ---- serial walk within the chunk (<=16 bins, thread 0) ----
    if (tid == 0) {
        const int t   = s_b;
        int acc = s_above;
        int b = t * CHW, r = k - acc;  // fallback (never used)
        for (int j = CHW - 1; j >= 0; --j) {
            const int bin = t * CHW + j;
            const int cb  = cnt[bin];
            if (acc + cb >= k) { b = bin; r = k - acc; break; }
            acc += cb;
        }
        s_b = b; s_r = r;
    }
    __syncthreads();
    const int b = s_b;
    const int r = s_r;

    // ---- Pass B: sum of bins > b, collect bin b ----
    float lsum = 0.f;
#define PROC(x) do { \
        const float _x = (x); \
        const int _bn = BIN(_x); \
        if (_bn > b) lsum += _x; \
        else if (_bn == b) { \
            int p = atomicAdd(&s_ccount, 1); \
            if (p < CAP) buf[p] = _x; \
        } \
    } while (0)

    for (int j = tid; j < n4; j += BLK) {
        float4 v = rp4[j];
        PROC(v.x); PROC(v.y); PROC(v.z); PROC(v.w);
    }
    for (int j = (n4 << 2) + tid; j < n; j += BLK) PROC(rp[j]);
#undef PROC

    // block reduction of lsum (wave64 shuffle, then 4 partials via LDS)
    for (int off = 32; off > 0; off >>= 1) lsum += __shfl_down(lsum, off, 64);
    if ((tid & 63) == 0) wsum[tid >> 6] = lsum;
    __syncthreads();

    // ---- epilogue (thread 0) ----
    if (tid == 0) {
        float above_sum = wsum[0] + wsum[1] + wsum[2] + wsum[3];
        const int m  = s_ccount;           // == cnt[b]
        const int mm = min(m, CAP);
        const int rr = min(r, mm);
        float top = 0.f;
        for (int s = 0; s < rr; ++s) {     // r <= cnt[b] ~ O(8..30) in practice
            float best = -1.f; int bi = 0;
            for (int j = 0; j < mm; ++j) {
                const float x = buf[j];
                if (x > best) { best = x; bi = j; }
            }
            top += best;
            buf[bi] = -1.f;
        }
        if (r > rr) {
            // pathological overflow fallback: bounded error r/NB in the sum
            top += (float)(r - rr) * ((float)(b) + 0.5f) * (1.0f / NB);
        }
        float v = (above_sum + top) / (float)k;
        v = fminf(fmaxf(v, 1e-12f), 1.0f - 1e-7f);
        const float lab  = label[row];
        const float loss = -(lab * logf(v) + (1.0f - lab) * log1pf(-v));
        atomicAdd(out, loss / (float)B);   // device-scope, cross-XCD safe
    }
#undef BIN
}

extern "C" void kernel_launch(void* const* d_in, const int* in_sizes, int n_in,
                              void* d_out, int out_size, void* d_ws, size_t ws_size,
                              hipStream_t stream) {
    const float* scores = (const float*)d_in[0];
    const float* label  = (const float*)d_in[1];
    const int*   seqlen = (const int*)d_in[2];
    float* out = (float*)d_out;

    const int B = in_sizes[1];
    const int T = in_sizes[0] / B;

    // d_out is re-poisoned (0xAA) before every timed launch: zero it with a
    // kernel (no runtime API calls inside kernel_launch -> graph-capture safe).
    zero_out_kernel<<<1, 1, 0, stream>>>(out);
    topk_bce_kernel<<<B, BLK, 0, stream>>>(scores, label, seqlen, out, T, B);
}